// Round 5
// baseline (185.219 us; speedup 1.0000x reference)
//
#include <hip/hip_runtime.h>
#include <math.h>

// TripletLoss N=8192, D=128, labels in [0,512). Round 5: R4's LDS-staged MFMA
// structure with the scratch-spill bug fixed — R4's msq[b]/mlab[b] dynamic
// indexing in a rolled loop demoted the meta arrays to scratch (100+ MB of
// HBM traffic = the whole 133 us). Now: manual unroll-by-2 ping-pong with
// NAMED register sets and literal LDS buffer indices. No dynamic local
// indexing anywhere.
//   prep:   sq[i]=||x_i||^2 fp32 (wave shuffle), xb=bf16(x).
//   pair:   block=256 thr=4 waves, i-tile 256, j-chunk 256 (JSPLIT=32),
//           8 steps x 32 j-rows; 8 KB tile staged global->reg->ds_write into
//           double-buffered LDS (272-B row stride). u = dot - 0.5*sq_j via
//           MFMA 16x16x32 bf16 with acc init = -0.5*sq_j (fp32 exact).
//           hardest_pos = min u over positives (self masked to +inf on the
//           wave-uniform diagonal tile), hardest_neg = max u over negatives.
//   reduce: min/max over 32 partials/row; valid = (mnp<inf && mxn>-inf);
//           32 plain partial sums. final: 1 small block. No atomics/memsets.

#define NROWS 8192
#define DIM   128
#define JSPLIT 32
#define JCHUNK (NROWS / JSPLIT)   // 256 j per y-block
#define JSTEP  32
#define NSTEP  (JCHUNK / JSTEP)   // 8 (even)
#define LDSROW 272                // 256 B row + 16 B pad

typedef short bf16x8 __attribute__((ext_vector_type(8)));
typedef float f32x4  __attribute__((ext_vector_type(4)));

static __device__ __forceinline__ unsigned short f2bf(float f) {
    unsigned u = __float_as_uint(f);
    unsigned r = (u + 0x7FFFu + ((u >> 16) & 1u)) >> 16;   // RNE
    return (unsigned short)r;
}

__global__ __launch_bounds__(256) void prep_kernel(
    const float* __restrict__ x, float* __restrict__ sq,
    unsigned short* __restrict__ xb) {
    int t = blockIdx.x * 256 + threadIdx.x;
    int row = t >> 5;
    int c = t & 31;
    float4 v = ((const float4*)x)[t];
    float ps = v.x * v.x + v.y * v.y + v.z * v.z + v.w * v.w;
#pragma unroll
    for (int s = 1; s < 32; s <<= 1) ps += __shfl_xor(ps, s, 64);
    if (c == 0) sq[row] = ps;
    ushort4 ob;
    ob.x = f2bf(v.x); ob.y = f2bf(v.y); ob.z = f2bf(v.z); ob.w = f2bf(v.w);
    ((ushort4*)xb)[t] = ob;
}

__global__ __launch_bounds__(256, 3) void pair_kernel(
    const unsigned short* __restrict__ xb, const float* __restrict__ sq,
    const int* __restrict__ labels,
    float* __restrict__ hpp, float* __restrict__ hnp) {
    __shared__ unsigned char Ab0[JSTEP * LDSROW];
    __shared__ unsigned char Ab1[JSTEP * LDSROW];

    const int tid = threadIdx.x;
    const int lane = tid & 63;
    const int wid = tid >> 6;
    const int q = lane >> 4;
    const int r = lane & 15;
    const int ibase = blockIdx.x * 256 + wid * 64;
    const int jbase = blockIdx.y * JCHUNK;

    // B-frags (i side), resident for the whole j-loop.
    bf16x8 bfrag[4][4];
    int labi[4];
#pragma unroll
    for (int sub = 0; sub < 4; ++sub) {
        int irow = ibase + sub * 16 + r;
        labi[sub] = labels[irow];
#pragma unroll
        for (int ks = 0; ks < 4; ++ks)
            bfrag[sub][ks] = *(const bf16x8*)(xb + (size_t)irow * DIM + ks * 32 + q * 8);
    }

    float hp[4] = {INFINITY, INFINITY, INFINITY, INFINITY};     // min u (pos)
    float hn[4] = {-INFINITY, -INFINITY, -INFINITY, -INFINITY}; // max u (neg)

    const int srow = tid >> 4;       // 0..15
    const int sseg = tid & 15;       // 0..15

    // Named ping-pong register sets — NO dynamically indexed locals.
    bf16x8 rgP0, rgP1, rgQ0, rgQ1;
    f32x4 sqP0, sqP1, sqQ0, sqQ1;
    int4 labP0, labP1, labQ0, labQ1;

#define GLOADP(j0) do { \
        rgP0 = *(const bf16x8*)(xb + (size_t)((j0) + srow) * DIM + sseg * 8); \
        rgP1 = *(const bf16x8*)(xb + (size_t)((j0) + srow + 16) * DIM + sseg * 8); \
        sqP0 = *(const f32x4*)(sq + (j0) + q * 4); \
        sqP1 = *(const f32x4*)(sq + (j0) + 16 + q * 4); \
        labP0 = *(const int4*)(labels + (j0) + q * 4); \
        labP1 = *(const int4*)(labels + (j0) + 16 + q * 4); \
    } while (0)
#define GLOADQ(j0) do { \
        rgQ0 = *(const bf16x8*)(xb + (size_t)((j0) + srow) * DIM + sseg * 8); \
        rgQ1 = *(const bf16x8*)(xb + (size_t)((j0) + srow + 16) * DIM + sseg * 8); \
        sqQ0 = *(const f32x4*)(sq + (j0) + q * 4); \
        sqQ1 = *(const f32x4*)(sq + (j0) + 16 + q * 4); \
        labQ0 = *(const int4*)(labels + (j0) + q * 4); \
        labQ1 = *(const int4*)(labels + (j0) + 16 + q * 4); \
    } while (0)
#define SWRITE(buf, g0, g1) do { \
        *(bf16x8*)&buf[srow * LDSROW + sseg * 16] = g0; \
        *(bf16x8*)&buf[(srow + 16) * LDSROW + sseg * 16] = g1; \
    } while (0)

    auto compute = [&](const unsigned char* buf, int j0,
                       const f32x4& sqj0, const f32x4& sqj1,
                       const int4& labj0, const int4& labj1) {
#pragma unroll
        for (int tt = 0; tt < 2; ++tt) {
            const int j16 = j0 + tt * 16;
            const unsigned char* lp = buf + (tt * 16 + r) * LDSROW + q * 16;
            bf16x8 af0 = *(const bf16x8*)(lp);
            bf16x8 af1 = *(const bf16x8*)(lp + 64);
            bf16x8 af2 = *(const bf16x8*)(lp + 128);
            bf16x8 af3 = *(const bf16x8*)(lp + 192);
            f32x4 sqj = tt ? sqj1 : sqj0;
            int4 labj = tt ? labj1 : labj0;
            f32x4 cinit;
            cinit[0] = -0.5f * sqj[0]; cinit[1] = -0.5f * sqj[1];
            cinit[2] = -0.5f * sqj[2]; cinit[3] = -0.5f * sqj[3];
#pragma unroll
            for (int sub = 0; sub < 4; ++sub) {
                f32x4 acc = cinit;
                acc = __builtin_amdgcn_mfma_f32_16x16x32_bf16(af0, bfrag[sub][0], acc, 0, 0, 0);
                acc = __builtin_amdgcn_mfma_f32_16x16x32_bf16(af1, bfrag[sub][1], acc, 0, 0, 0);
                acc = __builtin_amdgcn_mfma_f32_16x16x32_bf16(af2, bfrag[sub][2], acc, 0, 0, 0);
                acc = __builtin_amdgcn_mfma_f32_16x16x32_bf16(af3, bfrag[sub][3], acc, 0, 0, 0);
                const int li = labi[sub];
                float u0 = acc[0], u1 = acc[1], u2 = acc[2], u3 = acc[3];
                float p0 = u0, p1 = u1, p2 = u2, p3 = u3;
                if (j16 == ibase + sub * 16) {   // wave-uniform diagonal tile
                    int d = r - 4 * q;           // self element: reg == d
                    p0 = (d == 0) ? INFINITY : p0;
                    p1 = (d == 1) ? INFINITY : p1;
                    p2 = (d == 2) ? INFINITY : p2;
                    p3 = (d == 3) ? INFINITY : p3;
                }
                hp[sub] = fminf(hp[sub], (labj.x == li) ? p0 : INFINITY);
                hn[sub] = fmaxf(hn[sub], (labj.x == li) ? -INFINITY : u0);
                hp[sub] = fminf(hp[sub], (labj.y == li) ? p1 : INFINITY);
                hn[sub] = fmaxf(hn[sub], (labj.y == li) ? -INFINITY : u1);
                hp[sub] = fminf(hp[sub], (labj.z == li) ? p2 : INFINITY);
                hn[sub] = fmaxf(hn[sub], (labj.z == li) ? -INFINITY : u2);
                hp[sub] = fminf(hp[sub], (labj.w == li) ? p3 : INFINITY);
                hn[sub] = fmaxf(hn[sub], (labj.w == li) ? -INFINITY : u3);
            }
        }
    };

    GLOADP(jbase);
    SWRITE(Ab0, rgP0, rgP1);
    f32x4 csqP0 = sqP0, csqP1 = sqP1;
    int4 clabP0 = labP0, clabP1 = labP1;

    for (int s = 0; s < NSTEP; s += 2) {
        const int j0 = jbase + s * JSTEP;
        // phase A: compute from Ab0 (meta in csqP*/clabP*)
        GLOADQ(j0 + JSTEP);
        __syncthreads();                       // Ab0 writes visible; Ab1 reads done
        compute(Ab0, j0, csqP0, csqP1, clabP0, clabP1);
        SWRITE(Ab1, rgQ0, rgQ1);
        // phase B: compute from Ab1
        const bool more = (s + 2 < NSTEP);
        if (more) GLOADP(j0 + 2 * JSTEP);
        __syncthreads();                       // Ab1 writes visible; Ab0 reads done
        compute(Ab1, j0 + JSTEP, sqQ0, sqQ1, labQ0, labQ1);
        if (more) {
            SWRITE(Ab0, rgP0, rgP1);
            csqP0 = sqP0; csqP1 = sqP1; clabP0 = labP0; clabP1 = labP1;
        }
    }

    // reduce across the 4 q-groups (lanes r, r+16, r+32, r+48)
#pragma unroll
    for (int sub = 0; sub < 4; ++sub) {
        hp[sub] = fminf(hp[sub], __shfl_xor(hp[sub], 16, 64));
        hp[sub] = fminf(hp[sub], __shfl_xor(hp[sub], 32, 64));
        hn[sub] = fmaxf(hn[sub], __shfl_xor(hn[sub], 16, 64));
        hn[sub] = fmaxf(hn[sub], __shfl_xor(hn[sub], 32, 64));
    }
    if (lane < 16) {
        const int pbase = blockIdx.y * NROWS;
#pragma unroll
        for (int sub = 0; sub < 4; ++sub) {
            int irow = ibase + sub * 16 + lane;
            hpp[pbase + irow] = hp[sub];
            hnp[pbase + irow] = hn[sub];
        }
    }
#undef GLOADP
#undef GLOADQ
#undef SWRITE
}

__global__ __launch_bounds__(256) void reduce_kernel(
    const float* __restrict__ hpp, const float* __restrict__ hnp,
    const float* __restrict__ sq,
    float* __restrict__ rsum, float* __restrict__ rcnt) {
    int row = blockIdx.x * 256 + threadIdx.x;
    float mnp = INFINITY, mxn = -INFINITY;
#pragma unroll 8
    for (int p = 0; p < JSPLIT; ++p) {
        mnp = fminf(mnp, hpp[p * NROWS + row]);
        mxn = fmaxf(mxn, hnp[p * NROWS + row]);
    }
    float s = sq[row];
    float sum = 0.f, cnt = 0.f;
    if (mnp < INFINITY && mxn > -INFINITY) {   // == reference valid mask
        float dp = sqrtf(fmaxf(s - 2.f * mnp, 1e-12f));
        float dn = sqrtf(fmaxf(s - 2.f * mxn, 1e-12f));
        sum = fmaxf(dp - dn + 0.3f, 1e-6f);
        cnt = 1.f;
    }
#pragma unroll
    for (int sh = 1; sh < 64; sh <<= 1) {
        sum += __shfl_xor(sum, sh, 64);
        cnt += __shfl_xor(cnt, sh, 64);
    }
    __shared__ float ss[4], sc[4];
    int w = threadIdx.x >> 6;
    if ((threadIdx.x & 63) == 0) { ss[w] = sum; sc[w] = cnt; }
    __syncthreads();
    if (threadIdx.x == 0) {
        rsum[blockIdx.x] = ss[0] + ss[1] + ss[2] + ss[3];
        rcnt[blockIdx.x] = sc[0] + sc[1] + sc[2] + sc[3];
    }
}

__global__ void final_kernel(const float* __restrict__ rsum,
                             const float* __restrict__ rcnt,
                             float* __restrict__ out) {
    int t = threadIdx.x;   // 64 threads
    float s = (t < 32) ? rsum[t] : 0.f;
    float c = (t < 32) ? rcnt[t] : 0.f;
#pragma unroll
    for (int sh = 1; sh < 64; sh <<= 1) {
        s += __shfl_xor(s, sh, 64);
        c += __shfl_xor(c, sh, 64);
    }
    if (t == 0) out[0] = (c > 0.f) ? s / c : 0.f;
}

extern "C" void kernel_launch(void* const* d_in, const int* in_sizes, int n_in,
                              void* d_out, int out_size, void* d_ws, size_t ws_size,
                              hipStream_t stream) {
    const float* x = (const float*)d_in[0];
    const int* labels = (const int*)d_in[1];
    float* out = (float*)d_out;

    // ws layout (16-B aligned):
    //   sq   @ 0        (32 KB)
    //   rsum @ 32768, rcnt @ 33024
    //   hpp  @ 36864    (1 MB)   [JSPLIT x NROWS], fully written by pair
    //   hnp  @ 1085440  (1 MB)
    //   xb   @ 2134016  (2 MB bf16)
    char* ws = (char*)d_ws;
    float* sq = (float*)ws;
    float* rsum = (float*)(ws + 32768);
    float* rcnt = (float*)(ws + 33024);
    float* hpp = (float*)(ws + 36864);
    float* hnp = (float*)(ws + 1085440);
    unsigned short* xb = (unsigned short*)(ws + 2134016);

    prep_kernel<<<(NROWS * 32) / 256, 256, 0, stream>>>(x, sq, xb);
    pair_kernel<<<dim3(NROWS / 256, JSPLIT), 256, 0, stream>>>(xb, sq, labels, hpp, hnp);
    reduce_kernel<<<NROWS / 256, 256, 0, stream>>>(hpp, hnp, sq, rsum, rcnt);
    final_kernel<<<1, 64, 0, stream>>>(rsum, rcnt, out);
}

// Round 6
// 140.606 us; speedup vs baseline: 1.3173x; 1.3173x over previous
//
#include <hip/hip_runtime.h>
#include <math.h>

// TripletLoss N=8192, D=128, labels in [0,512). Round 6: kill the scratch
// spill by cutting register demand, not by capping the allocator.
//   R4/R5 lesson: 131 MB FETCH / 170 MB WRITE in pair == scratch spill.
//   launch_bounds(256,3) caps unified VGPR+AGPR at ~168; live set (bfrag 64
//   + staging 16 + meta 32 + 8 MFMA chains + addr) exceeded it.
// Changes:
//   - j-chunk meta (sq, labels: 2 KB) staged once into LDS; compute reads it
//     with broadcast ds_read (16 lanes same address — free). -32 VGPRs.
//   - 32 i-rows per wave (2 subs, x-grid 64): bfrag 64->32 VGPRs, 4 live
//     MFMA chains. Total work unchanged.
//   - launch_bounds(256,4): demand ~90 << 128 cap, 16 waves/CU.
// Structure otherwise as R5: double-buffered 8 KB LDS A-tiles (272-B row
// stride), named ping-pong staging regs, u = dot - 0.5*sq_j via MFMA
// 16x16x32 bf16 (acc init = -0.5*sq_j, fp32 exact), hardest_pos = min u over
// positives (self masked to +inf on the wave-uniform diagonal tile),
// hardest_neg = max u over negatives; d^2 = sq_i - 2u in reduce. Validity
// = (min_u < inf && max_u > -inf) == reference mask. No atomics, no memsets.

#define NROWS 8192
#define DIM   128
#define JSPLIT 32
#define JCHUNK (NROWS / JSPLIT)   // 256 j per y-block
#define JSTEP  32
#define NSTEP  (JCHUNK / JSTEP)   // 8 (even)
#define LDSROW 272                // 256 B row + 16 B pad
#define IBLK   128                // i-rows per block (32 per wave)

typedef short bf16x8 __attribute__((ext_vector_type(8)));
typedef float f32x4  __attribute__((ext_vector_type(4)));

static __device__ __forceinline__ unsigned short f2bf(float f) {
    unsigned u = __float_as_uint(f);
    unsigned r = (u + 0x7FFFu + ((u >> 16) & 1u)) >> 16;   // RNE
    return (unsigned short)r;
}

__global__ __launch_bounds__(256) void prep_kernel(
    const float* __restrict__ x, float* __restrict__ sq,
    unsigned short* __restrict__ xb) {
    int t = blockIdx.x * 256 + threadIdx.x;
    int row = t >> 5;
    int c = t & 31;
    float4 v = ((const float4*)x)[t];
    float ps = v.x * v.x + v.y * v.y + v.z * v.z + v.w * v.w;
#pragma unroll
    for (int s = 1; s < 32; s <<= 1) ps += __shfl_xor(ps, s, 64);
    if (c == 0) sq[row] = ps;
    ushort4 ob;
    ob.x = f2bf(v.x); ob.y = f2bf(v.y); ob.z = f2bf(v.z); ob.w = f2bf(v.w);
    ((ushort4*)xb)[t] = ob;
}

__global__ __launch_bounds__(256, 4) void pair_kernel(
    const unsigned short* __restrict__ xb, const float* __restrict__ sq,
    const int* __restrict__ labels,
    float* __restrict__ hpp, float* __restrict__ hnp) {
    __shared__ unsigned char Ab0[JSTEP * LDSROW];
    __shared__ unsigned char Ab1[JSTEP * LDSROW];
    __shared__ __align__(16) float sq_lds[JCHUNK];
    __shared__ __align__(16) int lab_lds[JCHUNK];

    const int tid = threadIdx.x;
    const int lane = tid & 63;
    const int wid = tid >> 6;
    const int q = lane >> 4;
    const int r = lane & 15;
    const int ibase = blockIdx.x * IBLK + wid * 32;
    const int jbase = blockIdx.y * JCHUNK;

    // B-frags (i side), resident for the whole j-loop: 2 subs x 4 k-steps.
    bf16x8 bfrag[2][4];
    int labi[2];
#pragma unroll
    for (int sub = 0; sub < 2; ++sub) {
        int irow = ibase + sub * 16 + r;
        labi[sub] = labels[irow];
#pragma unroll
        for (int ks = 0; ks < 4; ++ks)
            bfrag[sub][ks] = *(const bf16x8*)(xb + (size_t)irow * DIM + ks * 32 + q * 8);
    }

    float hp[2] = {INFINITY, INFINITY};     // min u over positives
    float hn[2] = {-INFINITY, -INFINITY};   // max u over negatives

    const int srow = tid >> 4;       // 0..15
    const int sseg = tid & 15;       // 0..15

    // Named ping-pong staging registers — no dynamically indexed locals.
    bf16x8 rgP0, rgP1, rgQ0, rgQ1;
#define GLOADP(j0) do { \
        rgP0 = *(const bf16x8*)(xb + (size_t)((j0) + srow) * DIM + sseg * 8); \
        rgP1 = *(const bf16x8*)(xb + (size_t)((j0) + srow + 16) * DIM + sseg * 8); \
    } while (0)
#define GLOADQ(j0) do { \
        rgQ0 = *(const bf16x8*)(xb + (size_t)((j0) + srow) * DIM + sseg * 8); \
        rgQ1 = *(const bf16x8*)(xb + (size_t)((j0) + srow + 16) * DIM + sseg * 8); \
    } while (0)
#define SWRITE(buf, g0, g1) do { \
        *(bf16x8*)&buf[srow * LDSROW + sseg * 16] = g0; \
        *(bf16x8*)&buf[(srow + 16) * LDSROW + sseg * 16] = g1; \
    } while (0)

    // jloc = j-offset within the chunk (0..224, step 32)
    auto compute = [&](const unsigned char* buf, int jloc) {
#pragma unroll
        for (int tt = 0; tt < 2; ++tt) {
            const int joff = jloc + tt * 16;
            const unsigned char* lp = buf + (tt * 16 + r) * LDSROW + q * 16;
            bf16x8 af0 = *(const bf16x8*)(lp);
            bf16x8 af1 = *(const bf16x8*)(lp + 64);
            bf16x8 af2 = *(const bf16x8*)(lp + 128);
            bf16x8 af3 = *(const bf16x8*)(lp + 192);
            f32x4 sqj = *(const f32x4*)&sq_lds[joff + q * 4];   // broadcast read
            int4 labj = *(const int4*)&lab_lds[joff + q * 4];   // broadcast read
            f32x4 cinit;
            cinit[0] = -0.5f * sqj[0]; cinit[1] = -0.5f * sqj[1];
            cinit[2] = -0.5f * sqj[2]; cinit[3] = -0.5f * sqj[3];
#pragma unroll
            for (int sub = 0; sub < 2; ++sub) {
                f32x4 acc = cinit;
                acc = __builtin_amdgcn_mfma_f32_16x16x32_bf16(af0, bfrag[sub][0], acc, 0, 0, 0);
                acc = __builtin_amdgcn_mfma_f32_16x16x32_bf16(af1, bfrag[sub][1], acc, 0, 0, 0);
                acc = __builtin_amdgcn_mfma_f32_16x16x32_bf16(af2, bfrag[sub][2], acc, 0, 0, 0);
                acc = __builtin_amdgcn_mfma_f32_16x16x32_bf16(af3, bfrag[sub][3], acc, 0, 0, 0);
                const int li = labi[sub];
                float u0 = acc[0], u1 = acc[1], u2 = acc[2], u3 = acc[3];
                float p0 = u0, p1 = u1, p2 = u2, p3 = u3;
                if (jbase + joff == ibase + sub * 16) {  // wave-uniform diag tile
                    int d = r - 4 * q;                   // self element: reg == d
                    p0 = (d == 0) ? INFINITY : p0;
                    p1 = (d == 1) ? INFINITY : p1;
                    p2 = (d == 2) ? INFINITY : p2;
                    p3 = (d == 3) ? INFINITY : p3;
                }
                hp[sub] = fminf(hp[sub], (labj.x == li) ? p0 : INFINITY);
                hn[sub] = fmaxf(hn[sub], (labj.x == li) ? -INFINITY : u0);
                hp[sub] = fminf(hp[sub], (labj.y == li) ? p1 : INFINITY);
                hn[sub] = fmaxf(hn[sub], (labj.y == li) ? -INFINITY : u1);
                hp[sub] = fminf(hp[sub], (labj.z == li) ? p2 : INFINITY);
                hn[sub] = fmaxf(hn[sub], (labj.z == li) ? -INFINITY : u2);
                hp[sub] = fminf(hp[sub], (labj.w == li) ? p3 : INFINITY);
                hn[sub] = fmaxf(hn[sub], (labj.w == li) ? -INFINITY : u3);
            }
        }
    };

    // Prologue: meta into LDS (one element per thread), first tile staged.
    sq_lds[tid] = sq[jbase + tid];
    lab_lds[tid] = labels[jbase + tid];
    GLOADP(jbase);
    SWRITE(Ab0, rgP0, rgP1);

    for (int s = 0; s < NSTEP; s += 2) {
        const int j0 = jbase + s * JSTEP;
        GLOADQ(j0 + JSTEP);
        __syncthreads();           // Ab0+meta writes visible; prior Ab1 reads done
        compute(Ab0, s * JSTEP);
        SWRITE(Ab1, rgQ0, rgQ1);
        const bool more = (s + 2 < NSTEP);
        if (more) GLOADP(j0 + 2 * JSTEP);
        __syncthreads();           // Ab1 writes visible; Ab0 reads done
        compute(Ab1, (s + 1) * JSTEP);
        if (more) SWRITE(Ab0, rgP0, rgP1);
    }

    // reduce across the 4 q-groups (lanes r, r+16, r+32, r+48)
#pragma unroll
    for (int sub = 0; sub < 2; ++sub) {
        hp[sub] = fminf(hp[sub], __shfl_xor(hp[sub], 16, 64));
        hp[sub] = fminf(hp[sub], __shfl_xor(hp[sub], 32, 64));
        hn[sub] = fmaxf(hn[sub], __shfl_xor(hn[sub], 16, 64));
        hn[sub] = fmaxf(hn[sub], __shfl_xor(hn[sub], 32, 64));
    }
    if (lane < 16) {
        const int pbase = blockIdx.y * NROWS;
#pragma unroll
        for (int sub = 0; sub < 2; ++sub) {
            int irow = ibase + sub * 16 + lane;
            hpp[pbase + irow] = hp[sub];
            hnp[pbase + irow] = hn[sub];
        }
    }
#undef GLOADP
#undef GLOADQ
#undef SWRITE
}

__global__ __launch_bounds__(256) void reduce_kernel(
    const float* __restrict__ hpp, const float* __restrict__ hnp,
    const float* __restrict__ sq,
    float* __restrict__ rsum, float* __restrict__ rcnt) {
    int row = blockIdx.x * 256 + threadIdx.x;
    float mnp = INFINITY, mxn = -INFINITY;
#pragma unroll 8
    for (int p = 0; p < JSPLIT; ++p) {
        mnp = fminf(mnp, hpp[p * NROWS + row]);
        mxn = fmaxf(mxn, hnp[p * NROWS + row]);
    }
    float s = sq[row];
    float sum = 0.f, cnt = 0.f;
    if (mnp < INFINITY && mxn > -INFINITY) {   // == reference valid mask
        float dp = sqrtf(fmaxf(s - 2.f * mnp, 1e-12f));
        float dn = sqrtf(fmaxf(s - 2.f * mxn, 1e-12f));
        sum = fmaxf(dp - dn + 0.3f, 1e-6f);
        cnt = 1.f;
    }
#pragma unroll
    for (int sh = 1; sh < 64; sh <<= 1) {
        sum += __shfl_xor(sum, sh, 64);
        cnt += __shfl_xor(cnt, sh, 64);
    }
    __shared__ float ss[4], sc[4];
    int w = threadIdx.x >> 6;
    if ((threadIdx.x & 63) == 0) { ss[w] = sum; sc[w] = cnt; }
    __syncthreads();
    if (threadIdx.x == 0) {
        rsum[blockIdx.x] = ss[0] + ss[1] + ss[2] + ss[3];
        rcnt[blockIdx.x] = sc[0] + sc[1] + sc[2] + sc[3];
    }
}

__global__ void final_kernel(const float* __restrict__ rsum,
                             const float* __restrict__ rcnt,
                             float* __restrict__ out) {
    int t = threadIdx.x;   // 64 threads
    float s = (t < 32) ? rsum[t] : 0.f;
    float c = (t < 32) ? rcnt[t] : 0.f;
#pragma unroll
    for (int sh = 1; sh < 64; sh <<= 1) {
        s += __shfl_xor(s, sh, 64);
        c += __shfl_xor(c, sh, 64);
    }
    if (t == 0) out[0] = (c > 0.f) ? s / c : 0.f;
}

extern "C" void kernel_launch(void* const* d_in, const int* in_sizes, int n_in,
                              void* d_out, int out_size, void* d_ws, size_t ws_size,
                              hipStream_t stream) {
    const float* x = (const float*)d_in[0];
    const int* labels = (const int*)d_in[1];
    float* out = (float*)d_out;

    // ws layout (16-B aligned):
    //   sq   @ 0        (32 KB)
    //   rsum @ 32768, rcnt @ 33024
    //   hpp  @ 36864    (1 MB)   [JSPLIT x NROWS], fully written by pair
    //   hnp  @ 1085440  (1 MB)
    //   xb   @ 2134016  (2 MB bf16)
    char* ws = (char*)d_ws;
    float* sq = (float*)ws;
    float* rsum = (float*)(ws + 32768);
    float* rcnt = (float*)(ws + 33024);
    float* hpp = (float*)(ws + 36864);
    float* hnp = (float*)(ws + 1085440);
    unsigned short* xb = (unsigned short*)(ws + 2134016);

    prep_kernel<<<(NROWS * 32) / 256, 256, 0, stream>>>(x, sq, xb);
    pair_kernel<<<dim3(NROWS / IBLK, JSPLIT), 256, 0, stream>>>(xb, sq, labels, hpp, hnp);
    reduce_kernel<<<NROWS / 256, 256, 0, stream>>>(hpp, hnp, sq, rsum, rcnt);
    final_kernel<<<1, 64, 0, stream>>>(rsum, rcnt, out);
}